// Round 4
// baseline (243.639 us; speedup 1.0000x reference)
//
#include <hip/hip_runtime.h>

// TernaryDense: out[N,U] = inputs[N,D] @ ternarize(w[D,U])
//   ternarize(w) = round(clip(w,-1,1)) round-half-to-even
//                = sign(w) if |w| > 0.5 else 0   (exact equivalence)
// N=8192, D=4096, U=4096, all f32.
//
// Glorot-uniform w has |w| <= sqrt(6/8192) ~= 0.027 < 0.5, so the ternarized
// weights are (discovered at runtime, never assumed) all-zero.
//
// Structure (read-stream || write-stream overlap):
//   kernel 1 (fused): each block scans a 64x128 region of w (flag per
//     (slice,stripe), written unconditionally) AND optimistically zero-fills
//     a linear 64 KiB chunk of out with nontemporal stores. One pass,
//     64 MiB read overlapped with 128 MiB write.
//   kernel 2 (fix-up): per 128x128 output tile, check the stripe's 64 flags;
//     all-zero -> return (zeros already written); else overwrite with a
//     correct dense f32 SGEMM fallback (CDNA4 has no fp32-input MFMA).

#define N_DIM 8192
#define D_DIM 4096
#define U_DIM 4096
#define BM 128
#define BN 128
#define BK 8
#define NSTRIPE (U_DIM / BN)    // 32 column stripes
#define NSLICE  64              // 64-row slices per stripe (4096/64)

typedef float vfloat4 __attribute__((ext_vector_type(4)));  // native vector
                                                            // (nontemporal ok)

// ---- kernel 1: fused scan + optimistic zero-fill ----
// grid 2048, block 256. Block b: slice = b>>5, stripe = b&31.
__global__ __launch_bounds__(256) void tz_scan_fill(const float* __restrict__ w,
                                                    int* __restrict__ flags,
                                                    float* __restrict__ out) {
    const int b = blockIdx.x;
    const int slice  = b >> 5;          // 0..63
    const int stripe = b & 31;          // 0..31
    const int t = threadIdx.x;
    const int row_stride4 = U_DIM / 4;  // 1024 float4 per w row

    // scan 64 rows x 128 cols of w: 2048 float4, 8 independent loads/thread
    const float4* w4 = reinterpret_cast<const float4*>(w) +
                       (size_t)(slice * 64) * row_stride4 + stripe * (BN / 4);
    bool nz = false;
    #pragma unroll
    for (int it = 0; it < 8; ++it) {
        int idx = t + it * 256;         // 0..2047
        int row = idx >> 5;             // 0..63
        int c4  = idx & 31;             // 0..31
        float4 v = w4[(size_t)row * row_stride4 + c4];
        nz |= (fabsf(v.x) > 0.5f) | (fabsf(v.y) > 0.5f) |
              (fabsf(v.z) > 0.5f) | (fabsf(v.w) > 0.5f);
    }

    // optimistic zero-fill: linear 64 KiB chunk (4096 vfloat4) of out
    vfloat4 z = (vfloat4)(0.0f);
    vfloat4* o4 = reinterpret_cast<vfloat4*>(out) + (size_t)b * 4096;
    #pragma unroll
    for (int it = 0; it < 16; ++it) {
        __builtin_nontemporal_store(z, &o4[it * 256 + t]);
    }

    // block-reduce nz flag, write unconditionally (no init, no atomics)
    __shared__ int wnz[4];
    bool anynz = __any(nz);             // wave64-uniform
    if ((t & 63) == 0) wnz[t >> 6] = anynz ? 1 : 0;
    __syncthreads();
    if (t == 0) flags[stripe * NSLICE + slice] = wnz[0] | wnz[1] | wnz[2] | wnz[3];
}

__device__ __forceinline__ float ternarize(float x) {
    return (fabsf(x) > 0.5f) ? copysignf(1.0f, x) : 0.0f;
}

// ---- kernel 2: fix-up (no-op when stripe all-zero) ----
__global__ __launch_bounds__(256, 4) void tz_fixup(const float* __restrict__ A,
                                                   const float* __restrict__ W,
                                                   const int* __restrict__ flags,
                                                   float* __restrict__ out) {
    const int bn = blockIdx.x;   // column stripe (0..31)
    const int bm = blockIdx.y;   // row block    (0..63)
    const int t  = threadIdx.x;

    // each wave reads all 64 slice-flags of this stripe -> uniform answer
    int p = flags[bn * NSLICE + (t & 63)];
    if (!__any(p != 0)) return;  // zeros already written by kernel 1

    // ---- dense fallback: f32 SGEMM with on-the-fly ternarization ----
    __shared__ float As[BK][BM];
    __shared__ float Bs[BK][BN];

    float acc[8][8];
    #pragma unroll
    for (int i = 0; i < 8; ++i)
        #pragma unroll
        for (int j = 0; j < 8; ++j) acc[i][j] = 0.0f;

    const int tm = (t >> 4) * 8;
    const int tn = (t & 15) * 8;

    const float* Ab = A + (size_t)bm * BM * D_DIM;
    const float* Wb = W + (size_t)bn * BN;

    const int a_row = t >> 1;
    const int a_k0  = (t & 1) * 4;
    const int b_kk  = t >> 5;
    const int b_n0  = (t & 31) * 4;

    for (int k0 = 0; k0 < D_DIM; k0 += BK) {
        float4 av = *reinterpret_cast<const float4*>(
            Ab + (size_t)a_row * D_DIM + k0 + a_k0);
        As[a_k0 + 0][a_row] = av.x;
        As[a_k0 + 1][a_row] = av.y;
        As[a_k0 + 2][a_row] = av.z;
        As[a_k0 + 3][a_row] = av.w;
        float4 bv = *reinterpret_cast<const float4*>(
            Wb + (size_t)(k0 + b_kk) * U_DIM + b_n0);
        Bs[b_kk][b_n0 + 0] = ternarize(bv.x);
        Bs[b_kk][b_n0 + 1] = ternarize(bv.y);
        Bs[b_kk][b_n0 + 2] = ternarize(bv.z);
        Bs[b_kk][b_n0 + 3] = ternarize(bv.w);
        __syncthreads();

        #pragma unroll
        for (int k = 0; k < BK; ++k) {
            float a[8], bb[8];
            #pragma unroll
            for (int i = 0; i < 8; ++i) a[i] = As[k][tm + i];
            #pragma unroll
            for (int jj = 0; jj < 8; ++jj) bb[jj] = Bs[k][tn + jj];
            #pragma unroll
            for (int i = 0; i < 8; ++i)
                #pragma unroll
                for (int jj = 0; jj < 8; ++jj) acc[i][jj] += a[i] * bb[jj];
        }
        __syncthreads();
    }

    #pragma unroll
    for (int i = 0; i < 8; ++i) {
        float* orow = out + (size_t)(bm * BM + tm + i) * U_DIM + bn * BN + tn;
        #pragma unroll
        for (int jj = 0; jj < 8; ++jj) orow[jj] = acc[i][jj];
    }
}

extern "C" void kernel_launch(void* const* d_in, const int* in_sizes, int n_in,
                              void* d_out, int out_size, void* d_ws, size_t ws_size,
                              hipStream_t stream) {
    const float* inputs = (const float*)d_in[0];   // [N, D] f32
    const float* w      = (const float*)d_in[1];   // [D, U] f32
    float* out          = (float*)d_out;           // [N, U] f32
    int* flags          = (int*)d_ws;              // NSTRIPE*NSLICE ints

    tz_scan_fill<<<2048, 256, 0, stream>>>(w, flags, out);

    dim3 fg(NSTRIPE, N_DIM / BM);
    tz_fixup<<<fg, 256, 0, stream>>>(inputs, w, flags, out);
}